// Round 1
// baseline (33.443 us; speedup 1.0000x reference)
//
#include <hip/hip_runtime.h>
#include <math.h>

// Problem dims (fixed by reference setup_inputs)
#define BB 32
#define LL 8192
#define DD 256
#define QQ 512
#define HH 256
#define MM 5
#define PRUNE_LEFT  (-50)
#define PRUNE_RIGHT (50)

// Kernel 1: per-batch tiny MLP.
// proj = tanh(query @ W1^T + b1)  (B,H);  stats = proj @ W2^T + b2 (B,15)
// ws[b*15 + j] = exp(stats[b][j])   (alpha | beta | kappa, 5 each)
__global__ void __launch_bounds__(HH) k_stats(const float* __restrict__ query,
                                              const float* __restrict__ W1,
                                              const float* __restrict__ b1,
                                              const float* __restrict__ W2,
                                              const float* __restrict__ b2,
                                              float* __restrict__ stats_out) {
    __shared__ float s_q[QQ];
    __shared__ float s_proj[HH];
    const int b = blockIdx.x;
    const int t = threadIdx.x;   // 256 threads, one per H row

    for (int i = t; i < QQ; i += HH) s_q[i] = query[b * QQ + i];
    __syncthreads();

    float acc = 0.f;
    const float* w1row = W1 + (size_t)t * QQ;
    #pragma unroll 8
    for (int q = 0; q < QQ; ++q) acc += s_q[q] * w1row[q];
    s_proj[t] = tanhf(acc + b1[t]);
    __syncthreads();

    if (t < 3 * MM) {
        float s = 0.f;
        const float* w2row = W2 + (size_t)t * HH;
        #pragma unroll 8
        for (int h = 0; h < HH; ++h) s += s_proj[h] * w2row[h];
        stats_out[b * (3 * MM) + t] = expf(s + b2[t]);
    }
}

// Kernel 2: dense p_ctx (B,L). Exact reference math including prune mask.
__global__ void __launch_bounds__(256) k_pctx(const float* __restrict__ stats,
                                              float* __restrict__ p_ctx) {
    const int b = blockIdx.y;
    const int l = blockIdx.x * 256 + threadIdx.x;
    if (l >= LL) return;
    const float* st = stats + b * (3 * MM);
    const float pos = (float)l;
    float p = 0.f;
    #pragma unroll
    for (int m = 0; m < MM; ++m) {
        const float alpha = st[m];
        const float beta  = st[MM + m];
        const float kappa = st[2 * MM + m];
        const float center = rintf(kappa);            // round-half-to-even, matches jnp.round
        const float left  = center + (float)PRUNE_LEFT;
        const float right = center + (float)(PRUNE_RIGHT + 1);
        if (pos >= left && pos < right) {
            const float diff = pos - kappa;
            p += alpha * expf(-beta * diff * diff);
        }
    }
    p_ctx[(size_t)b * LL + l] = p;
}

// Kernel 3: expected_ctx[b,d] = sum over the (exact) nonzero window of
// p_ctx[b,l] * ctx[b,l,d]. Window = union of per-mixture prune windows.
__global__ void __launch_bounds__(DD) k_expect(const float* __restrict__ ctx,
                                               const float* __restrict__ stats,
                                               const float* __restrict__ p_ctx,
                                               float* __restrict__ expected) {
    __shared__ int s_lo, s_hi;
    const int b = blockIdx.x;
    const int d = threadIdx.x;   // 256 threads, one per D column

    if (d == 0) {
        const float* st = stats + b * (3 * MM);
        float cmin = 1e30f, cmax = -1e30f;
        #pragma unroll
        for (int m = 0; m < MM; ++m) {
            const float c = rintf(st[2 * MM + m]);
            cmin = fminf(cmin, c);
            cmax = fmaxf(cmax, c);
        }
        float lof = fmaxf(0.f, cmin + (float)PRUNE_LEFT);
        float hif = fminf((float)LL, cmax + (float)(PRUNE_RIGHT + 1));
        int lo = (lof >= (float)LL) ? LL : (int)lof;
        int hi = (hif <= 0.f) ? 0 : (int)hif;
        if (hi < lo) hi = lo;
        s_lo = lo;
        s_hi = hi;
    }
    __syncthreads();

    const int lo = s_lo, hi = s_hi;
    float acc = 0.f;
    for (int l = lo; l < hi; ++l) {
        const float p = p_ctx[(size_t)b * LL + l];            // broadcast
        acc += p * ctx[((size_t)b * LL + l) * DD + d];        // coalesced 1KiB/row
    }
    expected[b * DD + d] = acc;
}

extern "C" void kernel_launch(void* const* d_in, const int* in_sizes, int n_in,
                              void* d_out, int out_size, void* d_ws, size_t ws_size,
                              hipStream_t stream) {
    const float* ctx   = (const float*)d_in[0];
    const float* query = (const float*)d_in[1];
    const float* W1    = (const float*)d_in[2];
    const float* b1    = (const float*)d_in[3];
    const float* W2    = (const float*)d_in[4];
    const float* b2    = (const float*)d_in[5];

    float* out      = (float*)d_out;
    float* expected = out;             // (B, D)  = 8192 floats
    float* p_ctx    = out + BB * DD;   // (B, L)  = 262144 floats
    float* stats    = (float*)d_ws;    // (B, 15) exp(stats) = alpha|beta|kappa

    k_stats<<<BB, HH, 0, stream>>>(query, W1, b1, W2, b2, stats);

    dim3 g2((LL + 255) / 256, BB);
    k_pctx<<<g2, 256, 0, stream>>>(stats, p_ctx);

    k_expect<<<BB, DD, 0, stream>>>(ctx, stats, p_ctx, expected);
}